// Round 1
// baseline (1023.058 us; speedup 1.0000x reference)
//
#include <hip/hip_runtime.h>
#include <stdint.h>

#define KVOL 27
#define CIN  32
#define COUT 32

// ---------------------------------------------------------------------------
// kmap_valid layout probe: JAX bool normally lands as 1-byte np.bool_, but a
// harness may widen to int32. If int32 with values {0,1}, bytes 1..3 of every
// 4-byte group are zero; if 1-byte bools those bytes are random 0/1.
// flag[0] = 1 -> int32 layout, 0 -> 1-byte layout. Written fresh every call
// (d_ws is re-poisoned to 0xAA before each timed launch).
// ---------------------------------------------------------------------------
__global__ void detect_valid_layout(const uint8_t* __restrict__ valid_bytes,
                                    int* __restrict__ flag) {
    __shared__ int s_sum;
    if (threadIdx.x == 0) s_sum = 0;
    __syncthreads();
    int local = 0;
    for (int g = threadIdx.x; g < 1024; g += 256) {
        local += valid_bytes[4 * g + 1] + valid_bytes[4 * g + 2] + valid_bytes[4 * g + 3];
    }
    atomicAdd(&s_sum, local);
    __syncthreads();
    if (threadIdx.x == 0) flag[0] = (s_sum == 0) ? 1 : 0;
}

// ---------------------------------------------------------------------------
// Baseline fp32 sparse conv: one voxel per thread, acc[32] in VGPRs.
// W[k][ci][co] is wave-uniform for fixed (k,ci) -> compiler emits scalar
// loads; x row gathered as 8x float4; invalid taps skip the gather entirely.
// ---------------------------------------------------------------------------
__global__ __launch_bounds__(256)
void sparse_conv_fp32(const float* __restrict__ X,
                      const float* __restrict__ W,
                      const float* __restrict__ B,
                      const int* __restrict__ idx,
                      const uint8_t* __restrict__ validb,
                      const int* __restrict__ flag,
                      float* __restrict__ out,
                      int N) {
    const int n = blockIdx.x * blockDim.x + threadIdx.x;
    if (n >= N) return;

    const bool int_layout = (flag[0] != 0);
    const int* validi = (const int*)validb;

    float acc[COUT];
#pragma unroll
    for (int co = 0; co < COUT; ++co) acc[co] = B[co];

    for (int k = 0; k < KVOL; ++k) {
        const size_t kn = (size_t)k * (size_t)N + (size_t)n;
        const int v = int_layout ? validi[kn] : (int)validb[kn];
        if (v) {
            const int j = idx[kn];
            const float4* xp = (const float4*)(X + (size_t)j * CIN);
            float xr[CIN];
#pragma unroll
            for (int q = 0; q < 8; ++q) {
                float4 t = xp[q];
                xr[4 * q + 0] = t.x;
                xr[4 * q + 1] = t.y;
                xr[4 * q + 2] = t.z;
                xr[4 * q + 3] = t.w;
            }
            const float* __restrict__ Wk = W + k * CIN * COUT;
#pragma unroll
            for (int ci = 0; ci < CIN; ++ci) {
                const float xv = xr[ci];
#pragma unroll
                for (int co = 0; co < COUT; ++co) {
                    acc[co] += xv * Wk[ci * COUT + co];
                }
            }
        }
    }

    float4* op = (float4*)(out + (size_t)n * COUT);
#pragma unroll
    for (int q = 0; q < 8; ++q) {
        op[q] = make_float4(acc[4 * q + 0], acc[4 * q + 1], acc[4 * q + 2], acc[4 * q + 3]);
    }
}

extern "C" void kernel_launch(void* const* d_in, const int* in_sizes, int n_in,
                              void* d_out, int out_size, void* d_ws, size_t ws_size,
                              hipStream_t stream) {
    const float*   X      = (const float*)d_in[0];   // (N, 32)
    const float*   W      = (const float*)d_in[1];   // (27, 32, 32)
    const float*   B      = (const float*)d_in[2];   // (32,)
    const int*     idx    = (const int*)d_in[3];     // (27, N)
    const uint8_t* validb = (const uint8_t*)d_in[4]; // (27, N) bool (layout probed)

    const int N = in_sizes[0] / CIN;
    int* flag = (int*)d_ws;

    detect_valid_layout<<<1, 256, 0, stream>>>(validb, flag);

    const int blocks = (N + 255) / 256;
    sparse_conv_fp32<<<blocks, 256, 0, stream>>>(X, W, B, idx, validb, flag,
                                                 (float*)d_out, N);
}

// Round 2
// 686.665 us; speedup vs baseline: 1.4899x; 1.4899x over previous
//
#include <hip/hip_runtime.h>
#include <stdint.h>

#define KVOL 27
#define CIN  32
#define COUT 32

typedef short bf16x8 __attribute__((ext_vector_type(8)));
typedef float f32x4  __attribute__((ext_vector_type(4)));

// ---------------------------------------------------------------------------
// kmap_valid layout probe (1-byte bool vs int32). flag[0]=1 -> int32 layout.
// ---------------------------------------------------------------------------
__global__ void detect_valid_layout(const uint8_t* __restrict__ valid_bytes,
                                    int* __restrict__ flag) {
    __shared__ int s_sum;
    if (threadIdx.x == 0) s_sum = 0;
    __syncthreads();
    int local = 0;
    for (int g = threadIdx.x; g < 1024; g += 256) {
        local += valid_bytes[4 * g + 1] + valid_bytes[4 * g + 2] + valid_bytes[4 * g + 3];
    }
    atomicAdd(&s_sum, local);
    __syncthreads();
    if (threadIdx.x == 0) flag[0] = (s_sum == 0) ? 1 : 0;
}

__device__ inline unsigned short f2bf(float f) {
    unsigned int u = __float_as_uint(f);
    return (unsigned short)((u + 0x7fffu + ((u >> 16) & 1u)) >> 16);
}

// X (N*32 fp32) -> Xb (N*32 bf16), 8 elements per thread, 16B stores.
__global__ __launch_bounds__(256)
void convert_x(const float* __restrict__ X, short* __restrict__ Xb, int n8) {
    int i = blockIdx.x * blockDim.x + threadIdx.x;
    if (i >= n8) return;
    const float4* p = (const float4*)X + 2 * (size_t)i;
    float4 f0 = p[0], f1 = p[1];
    bf16x8 o;
    o[0] = (short)f2bf(f0.x); o[1] = (short)f2bf(f0.y);
    o[2] = (short)f2bf(f0.z); o[3] = (short)f2bf(f0.w);
    o[4] = (short)f2bf(f1.x); o[5] = (short)f2bf(f1.y);
    o[6] = (short)f2bf(f1.z); o[7] = (short)f2bf(f1.w);
    *((bf16x8*)Xb + (size_t)i) = o;
}

// W (27,ci,co) fp32 -> Wt (27,co,ci) bf16
__global__ __launch_bounds__(256)
void convert_w(const float* __restrict__ W, short* __restrict__ Wt) {
    int i = blockIdx.x * blockDim.x + threadIdx.x; // i over 27*32*32
    if (i >= KVOL * CIN * COUT) return;
    int k  = i >> 10;
    int co = (i >> 5) & 31;
    int ci = i & 31;
    Wt[i] = (short)f2bf(W[k * 1024 + ci * 32 + co]);
}

// ---------------------------------------------------------------------------
// MFMA main: block=256 (4 waves). Each wave: 4 groups of 16 voxels, full 32
// output channels via 2 accumulators per group.
// A-frag (16x16x32): lane holds A[m=lane&15][k=(lane>>4)*8+j]  (16B gather)
// B-frag:            lane holds B[k=(lane>>4)*8+j][n=lane&15]  -> Wt[k][n][k0+j]
// C/D:               D[m=(lane>>4)*4+r][n=lane&15]
// ---------------------------------------------------------------------------
__global__ __launch_bounds__(256)
void sparse_conv_mfma(const short* __restrict__ Xb,
                      const short* __restrict__ Wt,
                      const float* __restrict__ bias,
                      const int* __restrict__ idx,
                      const uint8_t* __restrict__ validb,
                      const int* __restrict__ flag,
                      float* __restrict__ out, int N) {
    const int lane = threadIdx.x & 63;
    const int wave = threadIdx.x >> 6;
    const int col  = lane & 15;
    const int quad = lane >> 4;
    const int base = blockIdx.x * 256 + wave * 64;

    const bool int_layout = (flag[0] != 0);
    const int* validi = (const int*)validb;

    f32x4 acc[4][2] = {};
    const bf16x8 zero = {};

    for (int k = 0; k < KVOL; ++k) {
        const size_t koff = (size_t)k * (size_t)N;
        const bf16x8 b0 = *(const bf16x8*)(Wt + ((k * 32 + col)      * 32 + quad * 8));
        const bf16x8 b1 = *(const bf16x8*)(Wt + ((k * 32 + col + 16) * 32 + quad * 8));
        bf16x8 a[4];
#pragma unroll
        for (int g = 0; g < 4; ++g) {
            const int r = base + g * 16 + col;   // voxel row this lane gathers
            bool v = false;
            int  j = 0;
            if (r < N) {
                v = int_layout ? (validi[koff + r] != 0) : (validb[koff + r] != 0);
                j = idx[koff + r];
            }
            if (v) a[g] = *(const bf16x8*)(Xb + (size_t)j * CIN + quad * 8);
            else   a[g] = zero;
        }
#pragma unroll
        for (int g = 0; g < 4; ++g) {
            acc[g][0] = __builtin_amdgcn_mfma_f32_16x16x32_bf16(a[g], b0, acc[g][0], 0, 0, 0);
            acc[g][1] = __builtin_amdgcn_mfma_f32_16x16x32_bf16(a[g], b1, acc[g][1], 0, 0, 0);
        }
    }

    const float bv0 = bias[col];
    const float bv1 = bias[col + 16];
#pragma unroll
    for (int g = 0; g < 4; ++g) {
#pragma unroll
        for (int r = 0; r < 4; ++r) {
            const int row = base + g * 16 + quad * 4 + r;
            if (row < N) {
                out[(size_t)row * COUT + col]      = acc[g][0][r] + bv0;
                out[(size_t)row * COUT + col + 16] = acc[g][1][r] + bv1;
            }
        }
    }
}

// ---------------------------------------------------------------------------
// Fallback fp32 kernel (used only if ws_size is too small for bf16 staging).
// ---------------------------------------------------------------------------
__global__ __launch_bounds__(256)
void sparse_conv_fp32(const float* __restrict__ X,
                      const float* __restrict__ W,
                      const float* __restrict__ B,
                      const int* __restrict__ idx,
                      const uint8_t* __restrict__ validb,
                      const int* __restrict__ flag,
                      float* __restrict__ out,
                      int N) {
    const int n = blockIdx.x * blockDim.x + threadIdx.x;
    if (n >= N) return;
    const bool int_layout = (flag[0] != 0);
    const int* validi = (const int*)validb;
    float acc[COUT];
#pragma unroll
    for (int co = 0; co < COUT; ++co) acc[co] = B[co];
    for (int k = 0; k < KVOL; ++k) {
        const size_t kn = (size_t)k * (size_t)N + (size_t)n;
        const int v = int_layout ? validi[kn] : (int)validb[kn];
        if (v) {
            const int j = idx[kn];
            const float4* xp = (const float4*)(X + (size_t)j * CIN);
            float xr[CIN];
#pragma unroll
            for (int q = 0; q < 8; ++q) {
                float4 t = xp[q];
                xr[4 * q + 0] = t.x; xr[4 * q + 1] = t.y;
                xr[4 * q + 2] = t.z; xr[4 * q + 3] = t.w;
            }
            const float* __restrict__ Wk = W + k * CIN * COUT;
#pragma unroll
            for (int ci = 0; ci < CIN; ++ci) {
                const float xv = xr[ci];
#pragma unroll
                for (int co = 0; co < COUT; ++co) acc[co] += xv * Wk[ci * COUT + co];
            }
        }
    }
    float4* op = (float4*)(out + (size_t)n * COUT);
#pragma unroll
    for (int q = 0; q < 8; ++q)
        op[q] = make_float4(acc[4 * q + 0], acc[4 * q + 1], acc[4 * q + 2], acc[4 * q + 3]);
}

extern "C" void kernel_launch(void* const* d_in, const int* in_sizes, int n_in,
                              void* d_out, int out_size, void* d_ws, size_t ws_size,
                              hipStream_t stream) {
    const float*   X      = (const float*)d_in[0];   // (N, 32)
    const float*   W      = (const float*)d_in[1];   // (27, 32, 32)
    const float*   B      = (const float*)d_in[2];   // (32,)
    const int*     idx    = (const int*)d_in[3];     // (27, N)
    const uint8_t* validb = (const uint8_t*)d_in[4]; // (27, N)

    const int N = in_sizes[0] / CIN;

    const size_t xb_bytes = (size_t)N * CIN * sizeof(short);        // 64 MB
    const size_t wt_bytes = (size_t)KVOL * CIN * COUT * sizeof(short);
    const size_t need     = xb_bytes + wt_bytes + 256;

    if (ws_size >= need) {
        short* Xb  = (short*)d_ws;
        short* Wt  = (short*)((char*)d_ws + xb_bytes);
        int*   flag = (int*)((char*)d_ws + xb_bytes + wt_bytes);

        detect_valid_layout<<<1, 256, 0, stream>>>(validb, flag);

        const int n8 = (N * CIN) / 8;
        convert_x<<<(n8 + 255) / 256, 256, 0, stream>>>(X, Xb, n8);
        convert_w<<<(KVOL * CIN * COUT + 255) / 256, 256, 0, stream>>>(W, Wt);

        const int blocks = (N + 255) / 256;
        sparse_conv_mfma<<<blocks, 256, 0, stream>>>(Xb, Wt, B, idx, validb,
                                                     flag, (float*)d_out, N);
    } else {
        int* flag = (int*)d_ws;
        detect_valid_layout<<<1, 256, 0, stream>>>(validb, flag);
        const int blocks = (N + 255) / 256;
        sparse_conv_fp32<<<blocks, 256, 0, stream>>>(X, W, B, idx, validb,
                                                     flag, (float*)d_out, N);
    }
}